// Round 2
// baseline (458.612 us; speedup 1.0000x reference)
//
#include <hip/hip_runtime.h>
#include <math.h>

#define Hn 1024
#define En 1024
#define Ln 2048
#define Vn 50257

__device__ __forceinline__ float waveReduceSum(float v) {
#pragma unroll
    for (int off = 32; off > 0; off >>= 1)
        v += __shfl_down(v, off, 64);
    return v;
}

__device__ __forceinline__ float waveReduceMax(float v) {
#pragma unroll
    for (int off = 32; off > 0; off >>= 1)
        v = fmaxf(v, __shfl_down(v, off, 64));
    return v;
}

// ================= K1: fused d + attention scores =================
// grid (8 l-chunks, 16 e-chunks), block 256 (4 waves).
// Each block redundantly computes its 64 d-values (W_t re-read 8x -> L2/L3),
// then 256 score columns for its l-chunk.
__global__ __launch_bounds__(256) void k_d_scores(
    const float* __restrict__ h_i, const float* __restrict__ W_t,
    const float* __restrict__ b_t, const float* __restrict__ emb,
    const int* __restrict__ y, const float* __restrict__ cnn_a,
    float* __restrict__ part) {
    __shared__ float dsh[64];
    const int t = threadIdx.x, wave = t >> 6, lane = t & 63;
    const int e0 = blockIdx.y * 64;
    const float4* h4 = (const float4*)h_i;
    float4 hfrag[4];
#pragma unroll
    for (int k = 0; k < 4; ++k) hfrag[k] = h4[lane + k * 64];
    const int yy = y[0];
#pragma unroll 4
    for (int rr = 0; rr < 16; ++rr) {
        const int row = wave * 16 + rr;  // 0..63 within chunk
        const float4* wrow = (const float4*)(W_t + (size_t)(e0 + row) * Hn);
        float acc = 0.f;
#pragma unroll
        for (int k = 0; k < 4; ++k) {
            const float4 w = wrow[lane + k * 64];
            acc += w.x * hfrag[k].x + w.y * hfrag[k].y +
                   w.z * hfrag[k].z + w.w * hfrag[k].w;
        }
        acc = waveReduceSum(acc);
        if (lane == 0)
            dsh[row] = acc + b_t[e0 + row] + emb[(size_t)yy * Hn + e0 + row];
    }
    __syncthreads();
    const int l = blockIdx.x * 256 + t;
    float acc = 0.f;
#pragma unroll 8
    for (int e = 0; e < 64; ++e)
        acc += dsh[e] * cnn_a[(size_t)(e0 + e) * Ln + l];
    part[(size_t)blockIdx.y * Ln + l] = acc;
}

// ================= K2: fused softmax + context =================
// grid 1024 (one per h), block 256. Each block redundantly reduces the 16
// score partials (128 KB, L2-resident) into the full softmax, then dots
// with its cnn_c row.
__global__ __launch_bounds__(256) void k_softmax_c(
    const float* __restrict__ part, const float* __restrict__ cnn_c,
    float* __restrict__ c) {
    __shared__ float red[4];
    __shared__ float bc;
    const int t = threadIdx.x, wave = t >> 6, lane = t & 63;
    const int h = blockIdx.x;
    const float4* p4 = (const float4*)part;
    float4 r0 = {0.f, 0.f, 0.f, 0.f}, r1 = {0.f, 0.f, 0.f, 0.f};
#pragma unroll
    for (int p = 0; p < 16; ++p) {
        const float4 a = p4[p * 512 + t];
        const float4 b = p4[p * 512 + 256 + t];
        r0.x += a.x; r0.y += a.y; r0.z += a.z; r0.w += a.w;
        r1.x += b.x; r1.y += b.y; r1.z += b.z; r1.w += b.w;
    }
    // --- block max ---
    float m = fmaxf(fmaxf(fmaxf(r0.x, r0.y), fmaxf(r0.z, r0.w)),
                    fmaxf(fmaxf(r1.x, r1.y), fmaxf(r1.z, r1.w)));
    m = waveReduceMax(m);
    if (lane == 0) red[wave] = m;
    __syncthreads();
    if (t == 0) bc = fmaxf(fmaxf(red[0], red[1]), fmaxf(red[2], red[3]));
    __syncthreads();
    const float M = bc;
    // --- exp + block sum ---
    const float e0 = expf(r0.x - M), e1 = expf(r0.y - M);
    const float e2 = expf(r0.z - M), e3 = expf(r0.w - M);
    const float e4 = expf(r1.x - M), e5 = expf(r1.y - M);
    const float e6 = expf(r1.z - M), e7 = expf(r1.w - M);
    float s = e0 + e1 + e2 + e3 + e4 + e5 + e6 + e7;
    s = waveReduceSum(s);
    if (lane == 0) red[wave] = s;
    __syncthreads();
    if (t == 0) bc = red[0] + red[1] + red[2] + red[3];
    __syncthreads();
    const float inv = 1.0f / bc;
    // --- context dot ---
    const float4* crow = (const float4*)(cnn_c + (size_t)h * Ln);
    const float4 w0 = crow[t], w1 = crow[t + 256];
    float pc = e0 * w0.x + e1 * w0.y + e2 * w0.z + e3 * w0.w +
               e4 * w1.x + e5 * w1.y + e6 * w1.z + e7 * w1.w;
    pc = waveReduceSum(pc);
    if (lane == 0) red[wave] = pc;
    __syncthreads();
    if (t == 0) c[h] = (red[0] + red[1] + red[2] + red[3]) * inv;
}

// ================= K3: fused GRU matvecs + gates =================
// grid 1024 (one per hidden element i), block 256. Block i computes all
// three gate-row dots (r,z,n for W_ih and W_hh) and h_new[i] directly.
__global__ __launch_bounds__(256) void k_gru_fused(
    const float* __restrict__ emb, const int* __restrict__ y,
    const float* __restrict__ c, const float* __restrict__ h0,
    const float* __restrict__ W_ih, const float* __restrict__ W_hh,
    const float* __restrict__ b_ih, const float* __restrict__ b_hh,
    float* __restrict__ out_h) {
    __shared__ float redx[3][4], redh[3][4];
    const int t = threadIdx.x, wave = t >> 6, lane = t & 63;
    const int i = blockIdx.x;
    const float* g = emb + (size_t)y[0] * Hn;
    const float4 gv = ((const float4*)g)[t];
    const float4 cv = ((const float4*)c)[t];
    const float4 hv = ((const float4*)h0)[t];
    float ax[3], ah[3];
#pragma unroll
    for (int j = 0; j < 3; ++j) {
        const float4* wih = (const float4*)(W_ih + (size_t)(j * Hn + i) * (Hn + En));
        const float4 w0 = wih[t];
        const float4 w1 = wih[t + 256];
        ax[j] = w0.x * gv.x + w0.y * gv.y + w0.z * gv.z + w0.w * gv.w +
                w1.x * cv.x + w1.y * cv.y + w1.z * cv.z + w1.w * cv.w;
        const float4* whh = (const float4*)(W_hh + (size_t)(j * Hn + i) * Hn);
        const float4 w2 = whh[t];
        ah[j] = w2.x * hv.x + w2.y * hv.y + w2.z * hv.z + w2.w * hv.w;
    }
#pragma unroll
    for (int j = 0; j < 3; ++j) {
        ax[j] = waveReduceSum(ax[j]);
        ah[j] = waveReduceSum(ah[j]);
    }
    if (lane == 0) {
#pragma unroll
        for (int j = 0; j < 3; ++j) { redx[j][wave] = ax[j]; redh[j][wave] = ah[j]; }
    }
    __syncthreads();
    if (t == 0) {
        float gx[3], gh[3];
#pragma unroll
        for (int j = 0; j < 3; ++j) {
            gx[j] = redx[j][0] + redx[j][1] + redx[j][2] + redx[j][3] + b_ih[j * Hn + i];
            gh[j] = redh[j][0] + redh[j][1] + redh[j][2] + redh[j][3] + b_hh[j * Hn + i];
        }
        const float r = 1.f / (1.f + expf(-(gx[0] + gh[0])));
        const float z = 1.f / (1.f + expf(-(gx[1] + gh[1])));
        const float n = tanhf(gx[2] + r * gh[2]);
        out_h[i] = (1.f - z) * n + z * h0[i];
    }
}

// ================= K4: vocab logits =================
// 1024-thread blocks, 16 waves -> 16 rows each; grid ceil(V/16).
__global__ __launch_bounds__(1024) void k_logits(
    const float* __restrict__ W_o, const float* __restrict__ b_o,
    const float* __restrict__ hn, float* __restrict__ logits) {
    __shared__ float hsh[Hn];
    const int t = threadIdx.x;
    if (t < 256) ((float4*)hsh)[t] = ((const float4*)hn)[t];
    __syncthreads();
    const int wid = t >> 6, lane = t & 63;
    const int v = blockIdx.x * 16 + wid;
    if (v >= Vn) return;
    const float4* row = (const float4*)(W_o + (size_t)v * Hn);
    const float4* h4 = (const float4*)hsh;
    float acc = 0.f;
#pragma unroll
    for (int j = 0; j < 4; ++j) {
        const float4 w = row[lane + j * 64];
        const float4 hv = h4[lane + j * 64];
        acc += w.x * hv.x + w.y * hv.y + w.z * hv.z + w.w * hv.w;
    }
    acc = waveReduceSum(acc);
    if (lane == 0) logits[v] = acc + b_o[v];
}

// ================= K5: in-place log_softmax over V =================
// grid 1, block 1024, float4 main body + scalar tail (V = 4*12564 + 1).
__global__ __launch_bounds__(1024) void k_logsoftmax(float* __restrict__ out) {
    __shared__ float red[16];
    __shared__ float bc;
    const int t = threadIdx.x;
    float4* o4 = (float4*)out;
    const int N4 = Vn / 4;  // 12564
    float m = -INFINITY;
    for (int i = t; i < N4; i += 1024) {
        const float4 v = o4[i];
        m = fmaxf(m, fmaxf(fmaxf(v.x, v.y), fmaxf(v.z, v.w)));
    }
    if (t == 0) m = fmaxf(m, out[Vn - 1]);
    m = waveReduceMax(m);
    if ((t & 63) == 0) red[t >> 6] = m;
    __syncthreads();
    if (t == 0) {
        float mm = red[0];
#pragma unroll
        for (int i = 1; i < 16; ++i) mm = fmaxf(mm, red[i]);
        bc = mm;
    }
    __syncthreads();
    const float M = bc;
    float s = 0.f;
    for (int i = t; i < N4; i += 1024) {
        const float4 v = o4[i];
        s += expf(v.x - M) + expf(v.y - M) + expf(v.z - M) + expf(v.w - M);
    }
    if (t == 0) s += expf(out[Vn - 1] - M);
    s = waveReduceSum(s);
    if ((t & 63) == 0) red[t >> 6] = s;
    __syncthreads();
    if (t == 0) {
        float ss = 0.f;
#pragma unroll
        for (int i = 0; i < 16; ++i) ss += red[i];
        bc = M + logf(ss);
    }
    __syncthreads();
    const float lse = bc;
    for (int i = t; i < N4; i += 1024) {
        float4 v = o4[i];
        v.x -= lse; v.y -= lse; v.z -= lse; v.w -= lse;
        o4[i] = v;
    }
    if (t == 0) out[Vn - 1] -= lse;
}

extern "C" void kernel_launch(void* const* d_in, const int* in_sizes, int n_in,
                              void* d_out, int out_size, void* d_ws, size_t ws_size,
                              hipStream_t stream) {
    const int*   y     = (const int*)d_in[0];
    const float* h_i   = (const float*)d_in[1];
    const float* cnn_a = (const float*)d_in[2];
    const float* cnn_c = (const float*)d_in[3];
    const float* emb   = (const float*)d_in[4];
    const float* W_t   = (const float*)d_in[5];
    const float* b_t   = (const float*)d_in[6];
    const float* W_ih  = (const float*)d_in[7];
    const float* W_hh  = (const float*)d_in[8];
    const float* b_ih  = (const float*)d_in[9];
    const float* b_hh  = (const float*)d_in[10];
    const float* W_o   = (const float*)d_in[11];
    const float* b_o   = (const float*)d_in[12];
    float* out = (float*)d_out;

    float* ws    = (float*)d_ws;
    float* part  = ws;                 // 16*2048
    float* c_vec = part + 16 * Ln;     // 1024

    float* out_h = out + Vn;           // gru_hidden output, also input to K4

    k_d_scores<<<dim3(8, 16), dim3(256), 0, stream>>>(h_i, W_t, b_t, emb, y,
                                                      cnn_a, part);
    k_softmax_c<<<dim3(Hn), dim3(256), 0, stream>>>(part, cnn_c, c_vec);
    k_gru_fused<<<dim3(Hn), dim3(256), 0, stream>>>(emb, y, c_vec, h_i, W_ih,
                                                    W_hh, b_ih, b_hh, out_h);
    k_logits<<<dim3((Vn + 15) / 16), dim3(1024), 0, stream>>>(W_o, b_o, out_h, out);
    k_logsoftmax<<<dim3(1), dim3(1024), 0, stream>>>(out);
}

// Round 3
// 447.137 us; speedup vs baseline: 1.0257x; 1.0257x over previous
//
#include <hip/hip_runtime.h>
#include <math.h>

#define Hn 1024
#define En 1024
#define Ln 2048
#define Vn 50257
#define NLOGBLK ((Vn + 15) / 16)   // 3142 blocks in k_logits

__device__ __forceinline__ float waveReduceSum(float v) {
#pragma unroll
    for (int off = 32; off > 0; off >>= 1)
        v += __shfl_down(v, off, 64);
    return v;
}

__device__ __forceinline__ float waveReduceMax(float v) {
#pragma unroll
    for (int off = 32; off > 0; off >>= 1)
        v = fmaxf(v, __shfl_down(v, off, 64));
    return v;
}

// ================= K1: fused front-end =================
// grid 896 x 256 threads, three block roles:
//   b in [0,128):  d + attention scores.  ec = b>>3 (16 e-chunks), lc = b&7.
//   b in [128,512): gxg rows (W_ih[:, :H] . g + b_ih), 8 rows/block, 3072 rows.
//   b in [512,896): ghv rows (W_hh . h0 + b_hh),       8 rows/block, 3072 rows.
// Roles B/C are independent of attention — they overlap role A's low-parallelism phase.
__global__ __launch_bounds__(256) void k_front(
    const float* __restrict__ h_i, const float* __restrict__ W_t,
    const float* __restrict__ b_t, const float* __restrict__ emb,
    const int* __restrict__ y, const float* __restrict__ cnn_a,
    const float* __restrict__ W_ih, const float* __restrict__ W_hh,
    const float* __restrict__ b_ih, const float* __restrict__ b_hh,
    float* __restrict__ part, float* __restrict__ gxg, float* __restrict__ ghv) {
    __shared__ float dsh[64];
    const int b = blockIdx.x;
    const int t = threadIdx.x, wave = t >> 6, lane = t & 63;
    if (b < 128) {
        const int ec = b >> 3, lc = b & 7;
        const int e0 = ec * 64;
        const float4* h4 = (const float4*)h_i;
        float4 hfrag[4];
#pragma unroll
        for (int k = 0; k < 4; ++k) hfrag[k] = h4[lane + k * 64];
        const int yy = y[0];
#pragma unroll 4
        for (int rr = 0; rr < 16; ++rr) {
            const int row = wave * 16 + rr;  // 0..63 within chunk
            const float4* wrow = (const float4*)(W_t + (size_t)(e0 + row) * Hn);
            float acc = 0.f;
#pragma unroll
            for (int k = 0; k < 4; ++k) {
                const float4 w = wrow[lane + k * 64];
                acc += w.x * hfrag[k].x + w.y * hfrag[k].y +
                       w.z * hfrag[k].z + w.w * hfrag[k].w;
            }
            acc = waveReduceSum(acc);
            if (lane == 0)
                dsh[row] = acc + b_t[e0 + row] + emb[(size_t)yy * Hn + e0 + row];
        }
        __syncthreads();
        const int l = lc * 256 + t;
        float acc = 0.f;
#pragma unroll 8
        for (int e = 0; e < 64; ++e)
            acc += dsh[e] * cnn_a[(size_t)(e0 + e) * Ln + l];
        part[(size_t)ec * Ln + l] = acc;
    } else {
        const bool isB = (b < 512);
        const int rbase = (isB ? (b - 128) : (b - 512)) * 8;
        const float* xv = isB ? (emb + (size_t)y[0] * Hn) : h_i;
        const float4* x4 = (const float4*)xv;
        float4 xf[4];
#pragma unroll
        for (int k = 0; k < 4; ++k) xf[k] = x4[lane + k * 64];
        const size_t pitch = isB ? (size_t)(Hn + En) : (size_t)Hn;
        const float* Wm = isB ? W_ih : W_hh;
        const float* bias = isB ? b_ih : b_hh;
        float* outv = isB ? gxg : ghv;
#pragma unroll
        for (int rr = 0; rr < 2; ++rr) {
            const int r = rbase + wave * 2 + rr;
            const float4* wrow = (const float4*)(Wm + (size_t)r * pitch);
            float acc = 0.f;
#pragma unroll
            for (int k = 0; k < 4; ++k) {
                const float4 w = wrow[lane + k * 64];
                acc += w.x * xf[k].x + w.y * xf[k].y +
                       w.z * xf[k].z + w.w * xf[k].w;
            }
            acc = waveReduceSum(acc);
            if (lane == 0) outv[r] = acc + bias[r];
        }
    }
}

// ================= K2: fused softmax + context =================
// grid 1024 (one per h), block 256. Each block redundantly reduces the 16
// score partials (128 KB, L2-resident), then dots softmax(a) with its cnn_c row.
__global__ __launch_bounds__(256) void k_softmax_c(
    const float* __restrict__ part, const float* __restrict__ cnn_c,
    float* __restrict__ c) {
    __shared__ float red[4];
    __shared__ float bc;
    const int t = threadIdx.x, wave = t >> 6, lane = t & 63;
    const int h = blockIdx.x;
    const float4* p4 = (const float4*)part;
    float4 r0 = {0.f, 0.f, 0.f, 0.f}, r1 = {0.f, 0.f, 0.f, 0.f};
#pragma unroll
    for (int p = 0; p < 16; ++p) {
        const float4 a = p4[p * 512 + t];
        const float4 b = p4[p * 512 + 256 + t];
        r0.x += a.x; r0.y += a.y; r0.z += a.z; r0.w += a.w;
        r1.x += b.x; r1.y += b.y; r1.z += b.z; r1.w += b.w;
    }
    float m = fmaxf(fmaxf(fmaxf(r0.x, r0.y), fmaxf(r0.z, r0.w)),
                    fmaxf(fmaxf(r1.x, r1.y), fmaxf(r1.z, r1.w)));
    m = waveReduceMax(m);
    if (lane == 0) red[wave] = m;
    __syncthreads();
    if (t == 0) bc = fmaxf(fmaxf(red[0], red[1]), fmaxf(red[2], red[3]));
    __syncthreads();
    const float M = bc;
    const float e0 = expf(r0.x - M), e1 = expf(r0.y - M);
    const float e2 = expf(r0.z - M), e3 = expf(r0.w - M);
    const float e4 = expf(r1.x - M), e5 = expf(r1.y - M);
    const float e6 = expf(r1.z - M), e7 = expf(r1.w - M);
    float s = e0 + e1 + e2 + e3 + e4 + e5 + e6 + e7;
    s = waveReduceSum(s);
    if (lane == 0) red[wave] = s;
    __syncthreads();
    if (t == 0) bc = red[0] + red[1] + red[2] + red[3];
    __syncthreads();
    const float inv = 1.0f / bc;
    const float4* crow = (const float4*)(cnn_c + (size_t)h * Ln);
    const float4 w0 = crow[t], w1 = crow[t + 256];
    float pc = e0 * w0.x + e1 * w0.y + e2 * w0.z + e3 * w0.w +
               e4 * w1.x + e5 * w1.y + e6 * w1.z + e7 * w1.w;
    pc = waveReduceSum(pc);
    if (lane == 0) red[wave] = pc;
    __syncthreads();
    if (t == 0) c[h] = (red[0] + red[1] + red[2] + red[3]) * inv;
}

// ================= K3: GRU finish =================
// grid 1024 (one per hidden element i), block 256. Only the c-half of W_ih
// remains (12.6 MB); g/h0 halves were precomputed in k_front (gxg, ghv).
__global__ __launch_bounds__(256) void k_gru_fin(
    const float* __restrict__ c, const float* __restrict__ h0,
    const float* __restrict__ W_ih,
    const float* __restrict__ gxg, const float* __restrict__ ghv,
    float* __restrict__ out_h) {
    __shared__ float red[3][4];
    const int t = threadIdx.x, wave = t >> 6, lane = t & 63;
    const int i = blockIdx.x;
    const float4 cv = ((const float4*)c)[t];
    float a3[3];
#pragma unroll
    for (int j = 0; j < 3; ++j) {
        const float4* wrow =
            (const float4*)(W_ih + (size_t)(j * Hn + i) * (Hn + En) + Hn);
        const float4 w = wrow[t];
        a3[j] = w.x * cv.x + w.y * cv.y + w.z * cv.z + w.w * cv.w;
    }
#pragma unroll
    for (int j = 0; j < 3; ++j) a3[j] = waveReduceSum(a3[j]);
    if (lane == 0) {
        red[0][wave] = a3[0]; red[1][wave] = a3[1]; red[2][wave] = a3[2];
    }
    __syncthreads();
    if (t == 0) {
        float gx[3], gh[3];
#pragma unroll
        for (int j = 0; j < 3; ++j) {
            gx[j] = red[j][0] + red[j][1] + red[j][2] + red[j][3] + gxg[j * Hn + i];
            gh[j] = ghv[j * Hn + i];
        }
        const float r = 1.f / (1.f + expf(-(gx[0] + gh[0])));
        const float z = 1.f / (1.f + expf(-(gx[1] + gh[1])));
        const float n = tanhf(gx[2] + r * gh[2]);
        out_h[i] = (1.f - z) * n + z * h0[i];
    }
}

// ================= K4: vocab logits + per-block online-softmax partial ===========
// 1024-thread blocks, 16 waves -> 16 rows each; grid NLOGBLK.
// Each block also emits (m_b, s_b) so log_softmax needs no extra read pass.
__global__ __launch_bounds__(1024) void k_logits(
    const float* __restrict__ W_o, const float* __restrict__ b_o,
    const float* __restrict__ hn, float* __restrict__ logits,
    float2* __restrict__ blk_ms) {
    __shared__ float hsh[Hn];
    __shared__ float lsh[16];
    const int t = threadIdx.x;
    if (t < 256) ((float4*)hsh)[t] = ((const float4*)hn)[t];
    __syncthreads();
    const int wid = t >> 6, lane = t & 63;
    const int v = blockIdx.x * 16 + wid;
    float logit = -INFINITY;
    if (v < Vn) {
        const float4* row = (const float4*)(W_o + (size_t)v * Hn);
        const float4* h4 = (const float4*)hsh;
        float acc = 0.f;
#pragma unroll
        for (int j = 0; j < 4; ++j) {
            const float4 w = row[lane + j * 64];
            const float4 hv = h4[lane + j * 64];
            acc += w.x * hv.x + w.y * hv.y + w.z * hv.z + w.w * hv.w;
        }
        acc = waveReduceSum(acc);
        if (lane == 0) {
            logit = acc + b_o[v];
            logits[v] = logit;
        }
    }
    if (lane == 0) lsh[wid] = logit;
    __syncthreads();
    if (t == 0) {
        float m = lsh[0];
#pragma unroll
        for (int i = 1; i < 16; ++i) m = fmaxf(m, lsh[i]);
        float s = 0.f;
#pragma unroll
        for (int i = 0; i < 16; ++i) s += expf(lsh[i] - m);  // exp(-inf-m)=0 for pad
        blk_ms[blockIdx.x] = make_float2(m, s);
    }
}

// ================= K5: log_softmax finalize (parallel) =================
// grid 13 x 1024. Each block redundantly reduces the 3142 (m,s) pairs
// (25 KB, L2-resident) to the global LSE, then subtracts over its chunk.
__global__ __launch_bounds__(1024) void k_lsm_fin(
    const float2* __restrict__ blk_ms, float* __restrict__ out) {
    __shared__ float red_m[16], red_s[16];
    __shared__ float bc;
    const int t = threadIdx.x;
    float m = -INFINITY, s = 0.f;
    for (int i = t; i < NLOGBLK; i += 1024) {
        const float2 p = blk_ms[i];
        const float M = fmaxf(m, p.x);
        s = s * expf(m - M) + p.y * expf(p.x - M);
        m = M;
    }
#pragma unroll
    for (int off = 32; off > 0; off >>= 1) {
        const float om = __shfl_down(m, off, 64);
        const float os = __shfl_down(s, off, 64);
        const float M = fmaxf(m, om);
        s = s * expf(m - M) + os * expf(om - M);
        m = M;
    }
    if ((t & 63) == 0) { red_m[t >> 6] = m; red_s[t >> 6] = s; }
    __syncthreads();
    if (t == 0) {
        float M = red_m[0], S = red_s[0];
#pragma unroll
        for (int i = 1; i < 16; ++i) {
            const float M2 = fmaxf(M, red_m[i]);
            S = S * expf(M - M2) + red_s[i] * expf(red_m[i] - M2);
            M = M2;
        }
        bc = M + logf(S);
    }
    __syncthreads();
    const float lse = bc;
    const int N4 = Vn / 4;  // 12564
    const int i = blockIdx.x * 1024 + t;
    float4* o4 = (float4*)out;
    if (i < N4) {
        float4 v = o4[i];
        v.x -= lse; v.y -= lse; v.z -= lse; v.w -= lse;
        o4[i] = v;
    }
    if (blockIdx.x == 0 && t == 0) out[Vn - 1] -= lse;
}

extern "C" void kernel_launch(void* const* d_in, const int* in_sizes, int n_in,
                              void* d_out, int out_size, void* d_ws, size_t ws_size,
                              hipStream_t stream) {
    const int*   y     = (const int*)d_in[0];
    const float* h_i   = (const float*)d_in[1];
    const float* cnn_a = (const float*)d_in[2];
    const float* cnn_c = (const float*)d_in[3];
    const float* emb   = (const float*)d_in[4];
    const float* W_t   = (const float*)d_in[5];
    const float* b_t   = (const float*)d_in[6];
    const float* W_ih  = (const float*)d_in[7];
    const float* W_hh  = (const float*)d_in[8];
    const float* b_ih  = (const float*)d_in[9];
    const float* b_hh  = (const float*)d_in[10];
    const float* W_o   = (const float*)d_in[11];
    const float* b_o   = (const float*)d_in[12];
    float* out = (float*)d_out;

    float*  ws     = (float*)d_ws;
    float*  part   = ws;                    // 16*2048 = 32768
    float*  c_vec  = part + 16 * Ln;        // 1024
    float*  gxg    = c_vec + Hn;            // 3072
    float*  ghv    = gxg + 3 * Hn;          // 3072
    float2* blk_ms = (float2*)(ghv + 3 * Hn);  // 3142 float2

    float* out_h = out + Vn;  // gru_hidden output, also input to K4

    k_front<<<dim3(896), dim3(256), 0, stream>>>(h_i, W_t, b_t, emb, y, cnn_a,
                                                 W_ih, W_hh, b_ih, b_hh,
                                                 part, gxg, ghv);
    k_softmax_c<<<dim3(Hn), dim3(256), 0, stream>>>(part, cnn_c, c_vec);
    k_gru_fin<<<dim3(Hn), dim3(256), 0, stream>>>(c_vec, h_i, W_ih, gxg, ghv, out_h);
    k_logits<<<dim3(NLOGBLK), dim3(1024), 0, stream>>>(W_o, b_o, out_h, out, blk_ms);
    k_lsm_fin<<<dim3((Vn / 4 + 1023) / 1024), dim3(1024), 0, stream>>>(blk_ms, out);
}